// Round 8
// baseline (2742.862 us; speedup 1.0000x reference)
//
#include <hip/hip_runtime.h>

typedef _Float16 half_t;
typedef _Float16 h2_t __attribute__((ext_vector_type(2)));
typedef _Float16 h4_t __attribute__((ext_vector_type(4)));
typedef _Float16 h8_t __attribute__((ext_vector_type(8)));
typedef float f32x4 __attribute__((ext_vector_type(4)));
typedef unsigned int uint32;

#define BQ 64
#define TT 2048
#define EE 256
#define HH 256

#if defined(__has_builtin)
#if __has_builtin(__builtin_amdgcn_rcpf)
#define FRCP(x) __builtin_amdgcn_rcpf(x)
#endif
#endif
#ifndef FRCP
#define FRCP(x) (1.0f / (x))
#endif

// barrier that drains LDS only: global prefetch stays in flight
__device__ __forceinline__ void barrier_lgkm() {
  asm volatile("s_waitcnt lgkmcnt(0)\n\ts_barrier" ::: "memory");
}

__device__ __forceinline__ float sigmoid_f(float x) {
  return FRCP(1.f + __expf(-x));
}

__device__ __forceinline__ h8_t cvt_w8(const float* p) {
  float4 a0 = *(const float4*)p;
  float4 a1 = *(const float4*)(p + 4);
  h8_t w;
  w[0] = (half_t)a0.x; w[1] = (half_t)a0.y; w[2] = (half_t)a0.z; w[3] = (half_t)a0.w;
  w[4] = (half_t)a1.x; w[5] = (half_t)a1.y; w[6] = (half_t)a1.z; w[7] = (half_t)a1.w;
  return w;
}

#define MFMA16(a, b, c) __builtin_amdgcn_mfma_f32_16x16x32_f16((a), (b), (c), 0, 0, 0)

// ---------------- Phase A: input projections ----------------
// One block per timestep t: A (x rows, all 64 batches) staged ONCE, then 16
// N-chunks of 48 gate-rows with double-buffered, padded B tiles (x read 1x).
__device__ __forceinline__ const float4* wsrc(int n, int col, const float* Wu,
                                              const float* Wr, const float* Wn) {
  const int gsel = n >> 8, jj = n & 255;
  const float* W = (gsel == 0) ? Wu : (gsel == 1) ? Wr : Wn;
  return (const float4*)(W + (size_t)jj * (EE + HH) + col);
}

__global__ __launch_bounds__(256) void gru_xproj(
    const float* __restrict__ x,
    const float* __restrict__ Wu, const float* __restrict__ bu,
    const float* __restrict__ Wr, const float* __restrict__ br,
    const float* __restrict__ Wn, const float* __restrict__ bn,
    float* __restrict__ hs, half_t* __restrict__ nbuf, int t0)
{
  __shared__ half_t Asm[64][264];     // +8 pad: 2-way banks only
  __shared__ half_t Bsm[2][48][264];
  const int tid = threadIdx.x;
  const int tl = blockIdx.x;
  const int t = t0 + tl;

  // stage A: flat float4 index q = tid + 256k; row=q>>6 (batch), col=(q&63)*4
#pragma unroll
  for (int k = 0; k < 16; ++k) {
    int q = tid + 256 * k;
    int row = q >> 6, col = (q & 63) * 4;
    float4 v = *(const float4*)(x + ((size_t)row * TT + t) * EE + col);
    h4_t h; h[0] = (half_t)v.x; h[1] = (half_t)v.y; h[2] = (half_t)v.z; h[3] = (half_t)v.w;
    *(h4_t*)(&Asm[row][col]) = h;
  }
  // stage B chunk 0
#pragma unroll
  for (int k = 0; k < 12; ++k) {
    int q = tid + 256 * k;
    int row = q >> 6, col = (q & 63) * 4;
    float4 v = *wsrc(row, col, Wu, Wr, Wn);
    h4_t h; h[0] = (half_t)v.x; h[1] = (half_t)v.y; h[2] = (half_t)v.z; h[3] = (half_t)v.w;
    *(h4_t*)(&Bsm[0][row][col]) = h;
  }
  __syncthreads();

  const int wv = tid >> 6, lane = tid & 63;
  const int rowa = wv * 16 + (lane & 15);
  const int koff = (lane >> 4) * 8;
  h8_t af[8];
#pragma unroll
  for (int ki = 0; ki < 8; ++ki) af[ki] = *(const h8_t*)&Asm[rowa][ki * 32 + koff];

  const int colc = lane & 15;
  const int rbase = wv * 16 + (lane >> 4) * 4;

  for (int c = 0; c < 16; ++c) {
    const int cur = c & 1;
    // prefetch next B chunk into regs
    float4 pf[12];
    if (c < 15) {
#pragma unroll
      for (int k = 0; k < 12; ++k) {
        int q = tid + 256 * k;
        int row = q >> 6, col = (q & 63) * 4;
        pf[k] = *wsrc((c + 1) * 48 + row, col, Wu, Wr, Wn);
      }
    }
    // MFMA on current chunk
    f32x4 acc0 = {0.f, 0.f, 0.f, 0.f}, acc1 = acc0, acc2 = acc0;
#pragma unroll
    for (int ki = 0; ki < 8; ++ki) {
      h8_t b0 = *(const h8_t*)&Bsm[cur][0  + (lane & 15)][ki * 32 + koff];
      h8_t b1 = *(const h8_t*)&Bsm[cur][16 + (lane & 15)][ki * 32 + koff];
      h8_t b2 = *(const h8_t*)&Bsm[cur][32 + (lane & 15)][ki * 32 + koff];
      acc0 = MFMA16(af[ki], b0, acc0);
      acc1 = MFMA16(af[ki], b1, acc1);
      acc2 = MFMA16(af[ki], b2, acc2);
    }
    // write prefetched chunk to the other buffer
    if (c < 15) {
#pragma unroll
      for (int k = 0; k < 12; ++k) {
        int q = tid + 256 * k;
        int row = q >> 6, col = (q & 63) * 4;
        float4 v = pf[k];
        h4_t h; h[0] = (half_t)v.x; h[1] = (half_t)v.y; h[2] = (half_t)v.z; h[3] = (half_t)v.w;
        *(h4_t*)(&Bsm[cur ^ 1][row][col]) = h;
      }
    }
    // epilogue for chunk c (D: col = lane&15, row = (lane>>4)*4 + reg)
#pragma unroll
    for (int nt = 0; nt < 3; ++nt) {
      f32x4 a = (nt == 0) ? acc0 : (nt == 1) ? acc1 : acc2;
      int n = c * 48 + nt * 16 + colc;
      int gsel = n >> 8, jj = n & 255;
      const float* bp = (gsel == 0) ? bu : (gsel == 1) ? br : bn;
      float bias = bp[jj];
#pragma unroll
      for (int rr = 0; rr < 4; ++rr) {
        int m = rbase + rr;  // batch
        half_t hv = (half_t)(a[rr] + bias);
        if (gsel < 2) {
          ((unsigned short*)hs)[(((size_t)m * TT + t) * HH + jj) * 2 + gsel] =
              __builtin_bit_cast(unsigned short, hv);
        } else {
          nbuf[((size_t)tl * BQ + m) * HH + jj] = hv;
        }
      }
    }
    __syncthreads();
  }
}

// ---------------- Phase B: sequential scan via MFMA, latency-tuned ----------------
// One block per batch, 512 threads (8 waves). Wave w owns gate rows
// [32w, 32w+32) (two 16-col tiles) of u, r, n. Matvec = MFMA with h broadcast
// into all A-rows (K-reduction inside the matrix unit, no cross-lane reduce).
// Latency tuning vs R7:
//  - phase 1 = u-matvec ONLY (rt path); r-matvec moved to phase 2 where it
//    overlaps the n-matvec (its input ha survives in registers).
//  - u chains split 4x2 (dep depth 2), r/n chains 2x4; only acc[0] is live so
//    combining costs 1-3 scalar adds.
//  - per-lane single-row tail: lane (q,c16) finishes row jm = n0+16*(q&1)+c16;
//    q=0/1 lanes split the LDS/global writes; halves the sigmoid/tanh chains.
// rt uses Wu/xu, zt uses Wr/xr (reference naming quirk); n input is (rt*h)@Wn_h^T.
__global__ __launch_bounds__(512, 2) void gru_rec(
    float* __restrict__ hs,           // u/r gate stash + h output
    const half_t* __restrict__ nbuf,  // n-gate chunk
    const float* __restrict__ h0,
    const float* __restrict__ Wu, const float* __restrict__ Wr,
    const float* __restrict__ Wn,
    float* __restrict__ ht, float* __restrict__ hws,
    int t0, int t1)
{
  __shared__ __align__(16) half_t h2buf[256];
  __shared__ __align__(16) half_t rh2buf[256];

  const int b = blockIdx.x;
  const int tid = threadIdx.x;
  const int w = tid >> 6;     // wave 0..7
  const int lane = tid & 63;
  const int c16 = lane & 15;  // column within 16-tile
  const int q = lane >> 4;    // k-slot 0..3 (A/B operand k-slice)
  const int n0 = 32 * w;      // gate-row base for this wave
  const int jm = n0 + 16 * (q & 1) + c16;  // the row this lane's tail owns

  // B-fragments: w?[ct][kt] = W[n0+ct*16+c16][EE + kt*32 + q*8 .. +8]
  h8_t wu[2][8], wr[2][8], wn[2][8];
#pragma unroll
  for (int ct = 0; ct < 2; ++ct) {
    const int j = n0 + ct * 16 + c16;
    const float* pu = Wu + (size_t)j * (EE + HH) + EE + q * 8;
    const float* pr = Wr + (size_t)j * (EE + HH) + EE + q * 8;
    const float* pn = Wn + (size_t)j * (EE + HH) + EE + q * 8;
#pragma unroll
    for (int kt = 0; kt < 8; ++kt) {
      wu[ct][kt] = cvt_w8(pu + kt * 32);
      wr[ct][kt] = cvt_w8(pr + kt * 32);
      wn[ct][kt] = cvt_w8(pn + kt * 32);
    }
  }

  float hm;
  {
    const float* hsrc = (t0 == 0) ? (h0 + (size_t)b * HH) : (hws + (size_t)b * HH);
    hm = hsrc[jm];
    if (tid < 256) h2buf[tid] = (half_t)hsrc[tid];
  }
  __syncthreads();

  const uint32* urp = (const uint32*)hs + ((size_t)b * TT + t0) * HH;
  const half_t* np = nbuf + (size_t)b * HH;
  float* hout = hs + ((size_t)b * TT + t0) * HH;

  const int nT = t1 - t0;
  uint32 ur0 = urp[jm];
  half_t xn0 = np[jm];
  const size_t s1 = (size_t)((nT > 1) ? 1 : 0);
  uint32 ur1 = urp[s1 * HH + jm];
  half_t xn1 = np[s1 * BQ * HH + jm];

  const f32x4 z4 = {0.f, 0.f, 0.f, 0.f};

  for (int tl = 0; tl < nT; ++tl) {
    const size_t t2 = (size_t)((tl + 2 < nT) ? (tl + 2) : (nT - 1));
    uint32 ur2 = urp[t2 * HH + jm];          // stays in flight across barriers
    half_t xn2 = np[t2 * BQ * HH + jm];

    // ---- phase 1: u matvec only (A = broadcast h); 4 chains of 2 per tile ----
    h8_t ha[8];
#pragma unroll
    for (int kt = 0; kt < 8; ++kt) ha[kt] = *(const h8_t*)(h2buf + kt * 32 + q * 8);
    f32x4 u00 = MFMA16(ha[1], wu[0][1], MFMA16(ha[0], wu[0][0], z4));
    f32x4 u01 = MFMA16(ha[3], wu[0][3], MFMA16(ha[2], wu[0][2], z4));
    f32x4 u02 = MFMA16(ha[5], wu[0][5], MFMA16(ha[4], wu[0][4], z4));
    f32x4 u03 = MFMA16(ha[7], wu[0][7], MFMA16(ha[6], wu[0][6], z4));
    f32x4 u10 = MFMA16(ha[1], wu[1][1], MFMA16(ha[0], wu[1][0], z4));
    f32x4 u11 = MFMA16(ha[3], wu[1][3], MFMA16(ha[2], wu[1][2], z4));
    f32x4 u12 = MFMA16(ha[5], wu[1][5], MFMA16(ha[4], wu[1][4], z4));
    f32x4 u13 = MFMA16(ha[7], wu[1][7], MFMA16(ha[6], wu[1][6], z4));
    float suA = (u00[0] + u01[0]) + (u02[0] + u03[0]);
    float suB = (u10[0] + u11[0]) + (u12[0] + u13[0]);
    float sum = (q & 1) ? suB : suA;
    float xum = (float)__builtin_bit_cast(half_t, (unsigned short)(ur0 & 0xffffu));
    float rtm = sigmoid_f(xum + sum);
    if (q < 2) rh2buf[jm] = (half_t)(rtm * hm);  // rt * h (pre-matmul!)
    barrier_lgkm();

    // ---- phase 2: r matvec (from ha regs) + n matvec (from rh2buf) ----
    h8_t ra[8];
#pragma unroll
    for (int kt = 0; kt < 8; ++kt) ra[kt] = *(const h8_t*)(rh2buf + kt * 32 + q * 8);
    f32x4 r00 = z4, r01 = z4, r10 = z4, r11 = z4;
#pragma unroll
    for (int kt = 0; kt < 4; ++kt) {
      r00 = MFMA16(ha[kt], wr[0][kt], r00);
      r10 = MFMA16(ha[kt], wr[1][kt], r10);
    }
#pragma unroll
    for (int kt = 4; kt < 8; ++kt) {
      r01 = MFMA16(ha[kt], wr[0][kt], r01);
      r11 = MFMA16(ha[kt], wr[1][kt], r11);
    }
    f32x4 n00 = z4, n01 = z4, n10 = z4, n11 = z4;
#pragma unroll
    for (int kt = 0; kt < 4; ++kt) {
      n00 = MFMA16(ra[kt], wn[0][kt], n00);
      n10 = MFMA16(ra[kt], wn[1][kt], n10);
    }
#pragma unroll
    for (int kt = 4; kt < 8; ++kt) {
      n01 = MFMA16(ra[kt], wn[0][kt], n01);
      n11 = MFMA16(ra[kt], wn[1][kt], n11);
    }
    float srA = r00[0] + r01[0], srB = r10[0] + r11[0];
    float snA = n00[0] + n01[0], snB = n10[0] + n11[0];
    float srm = (q & 1) ? srB : srA;
    float snm = (q & 1) ? snB : snA;
    float xrm = (float)__builtin_bit_cast(half_t, (unsigned short)(ur0 >> 16));
    float ztm = sigmoid_f(xrm + srm);
    float prem = (float)xn0 + snm;
    prem = fminf(fmaxf(prem, -15.f), 15.f);
    float e = __expf(-2.f * prem);
    float nvm = (1.f - e) * FRCP(1.f + e);  // tanh
    float hnm = nvm + ztm * (hm - nvm);     // (1-z)*n + z*h
    hm = hnm;
    if (q < 2) {
      h2buf[jm] = (half_t)hnm;
      hout[(size_t)tl * HH + jm] = hnm;  // overwrites the consumed u/r slot
    }
    barrier_lgkm();

    ur0 = ur1; ur1 = ur2;
    xn0 = xn1; xn1 = xn2;
  }

  if (q < 2) {
    float* dst = (t1 == TT) ? (ht + (size_t)b * HH) : (hws + (size_t)b * HH);
    dst[jm] = hm;
  }
}

extern "C" void kernel_launch(void* const* d_in, const int* in_sizes, int n_in,
                              void* d_out, int out_size, void* d_ws, size_t ws_size,
                              hipStream_t stream)
{
  (void)in_sizes; (void)n_in; (void)out_size;
  const float* x  = (const float*)d_in[0];
  const float* h0 = (const float*)d_in[1];
  const float* Wu = (const float*)d_in[2];
  const float* bu = (const float*)d_in[3];
  const float* Wr = (const float*)d_in[4];
  const float* br = (const float*)d_in[5];
  const float* Wn = (const float*)d_in[6];
  const float* bn = (const float*)d_in[7];
  float* hs = (float*)d_out;
  float* ht = hs + (size_t)BQ * TT * HH;
  float* hws = (float*)d_ws;                      // 64 KB h carry
  half_t* nbuf = (half_t*)((char*)d_ws + 65536);  // n-gate chunks

  const size_t per_step = (size_t)BQ * HH * sizeof(half_t);  // 32 KB/step
  size_t avail = (ws_size > 65536) ? ws_size - 65536 : 0;
  int Tc = (int)(avail / per_step);
  if (Tc > TT) Tc = TT;
  if (Tc < 1) Tc = 1;

  for (int t0 = 0; t0 < TT; t0 += Tc) {
    int tc = (TT - t0 < Tc) ? (TT - t0) : Tc;
    gru_xproj<<<dim3(tc), 256, 0, stream>>>(x, Wu, bu, Wr, br, Wn, bn, hs, nbuf, t0);
    gru_rec<<<dim3(BQ), 512, 0, stream>>>(hs, nbuf, h0, Wu, Wr, Wn, ht, hws, t0, t0 + tc);
  }
}